// Round 7
// baseline (6706.948 us; speedup 1.0000x reference)
//
#include <hip/hip_runtime.h>
#include <hip/hip_bf16.h>

#define VOCAB 32000
#define EMB   128
#define HID   256
#define G4H   1024
#define BS    8
#define SEQ   1024

typedef __attribute__((ext_vector_type(8))) short short8;
typedef __attribute__((ext_vector_type(4))) float f32x4;
typedef __attribute__((ext_vector_type(2))) int   i32x2;

static __device__ __forceinline__ unsigned short f2bf(float x) {
  union { __hip_bfloat16 b; unsigned short u; } cv;
  cv.b = __float2bfloat16(x);
  return cv.u;
}
static __device__ __forceinline__ float bf2f(unsigned short u) {
  union { unsigned short u; __hip_bfloat16 b; } cv;
  cv.u = u;
  return __bfloat162float(cv.b);
}

static __device__ __forceinline__ float fsigmoid(float x) {
  return 1.f / (1.f + __expf(-x));
}
static __device__ __forceinline__ float ftanh(float x) {
  return 2.f / (1.f + __expf(-2.f * x)) - 1.f;
}

// ---- LLC-direct helpers (bypass both cache levels; coherence point).
static __device__ __forceinline__ int ld_int_cc(const int* p) {
  int r;
  asm volatile("global_load_dword %0, %1, off sc0 sc1\n\ts_waitcnt vmcnt(0)"
               : "=v"(r) : "v"(p) : "memory");
  return r;
}
static __device__ __forceinline__ void st_int_cc(int* p, int v) {
  asm volatile("global_store_dword %0, %1, off sc0 sc1" :: "v"(p), "v"(v) : "memory");
}
static __device__ __forceinline__ short8 ld16_cc(const unsigned short* p) {
  short8 r;
  asm volatile("global_load_dwordx4 %0, %1, off sc0 sc1" : "=v"(r) : "v"(p) : "memory");
  return r;
}
static __device__ __forceinline__ void st8_cc(unsigned short* p, i32x2 v) {
  asm volatile("global_store_dwordx2 %0, %1, off sc0 sc1" :: "v"(p), "v"(v) : "memory");
}

// ---------------- Kernel 1: embedding gather + x@W + bias -> xW (f32, in d_out scratch)
__global__ __launch_bounds__(256) void k_embed_xw(
    const int* __restrict__ sent, const float* __restrict__ wemb,
    const float* __restrict__ W, const float* __restrict__ bias,
    float* __restrict__ xW) {
  int tid = threadIdx.x;
  int blk = blockIdx.x;          // 2048 blocks
  int b  = blk >> 8;
  int t0 = (blk & 255) << 2;     // 4 timesteps per block
  __shared__ float xs[4][EMB];
  #pragma unroll
  for (int i = 0; i < 2; ++i) {
    int flat = tid + (i << 8);
    int r = flat >> 7, e = flat & 127;
    int idx = sent[b * SEQ + t0 + r];
    xs[r][e] = wemb[idx * EMB + e];
  }
  __syncthreads();
  int g0 = tid << 2;
  float acc[4][4] = {};
  for (int e = 0; e < EMB; ++e) {
    float4 w4 = *(const float4*)&W[e * G4H + g0];
    #pragma unroll
    for (int r = 0; r < 4; ++r) {
      float xv = xs[r][e];
      acc[r][0] += xv * w4.x; acc[r][1] += xv * w4.y;
      acc[r][2] += xv * w4.z; acc[r][3] += xv * w4.w;
    }
  }
  float4 bi = *(const float4*)&bias[g0];
  #pragma unroll
  for (int r = 0; r < 4; ++r) {
    float4 o;
    o.x = acc[r][0] + bi.x; o.y = acc[r][1] + bi.y;
    o.z = acc[r][2] + bi.z; o.w = acc[r][3] + bi.w;
    *(float4*)&xW[(size_t)(b * SEQ + t0 + r) * G4H + g0] = o;
  }
}

// ---------------- Kernel 2: w_linear (256 x 32000 f32) -> BT (32000 x 256 bf16)
__global__ __launch_bounds__(256) void k_transpose_w(
    const float* __restrict__ w, unsigned short* __restrict__ BT) {
  __shared__ unsigned short tile[64][66];
  int n0 = blockIdx.x * 64, k0 = blockIdx.y * 64;
  int tid = threadIdx.x;
  #pragma unroll
  for (int i = 0; i < 16; ++i) {
    int flat = tid + i * 256;
    int kk = flat >> 6, nn = flat & 63;
    tile[kk][nn] = f2bf(w[(size_t)(k0 + kk) * VOCAB + n0 + nn]);
  }
  __syncthreads();
  #pragma unroll
  for (int i = 0; i < 16; ++i) {
    int flat = tid + i * 256;
    int nn = flat >> 6, kk = flat & 63;
    BT[(size_t)(n0 + nn) * HID + k0 + kk] = tile[kk][nn];
  }
}

// ---------------- Kernel 3: persistent LSTM scan.
// 8 WGs x 512 threads = 64 waves; wave Wv owns hidden units [Wv*4, Wv*4+4) for
// all 4 gates (column-permuted U). Per step:
//   wave 0 of each WG polls the 64 per-wave flags (lane l watches flags[l])
//   -> ONE __syncthreads -> all waves dwordx4-load A-fragments directly from
//   hbuf/lbuf -> 3-chain MFMA -> intra-wave LDS transpose -> gates -> pack
//   2x dwordx2 records -> own vmcnt drain -> per-wave flag publish ->
//   (off-path) hidden store + next xW prefetch.
__global__ __launch_bounds__(512) void k_scan(
    const float* __restrict__ xW, const float* __restrict__ U,
    unsigned short* __restrict__ hidden,   // [8192][256] bf16
    unsigned short* __restrict__ hbuf,     // [2][8 bat][64 W][4] hi (padded)
    unsigned short* __restrict__ lbuf,     // [2][8 bat][64 W][4] lo (padded)
    int* __restrict__ flags) {             // [64] per-wave step counters
  const int tid = threadIdx.x;
  const int l = tid & 63, v = tid >> 6;
  const int Wv = blockIdx.x * 8 + v;       // global wave id 0..63

  // persistent U B-fragments (split bf16 hi/lo); wave's 16 cols:
  // c16 = hid_local*4 + gate  ->  U column = gate*HID + Wv*4 + hid_local
  const int c16 = l & 15;
  const int colU = (c16 & 3) * HID + Wv * 4 + (c16 >> 2);
  short8 bhi[8], blo[8];
  #pragma unroll
  for (int kb = 0; kb < 8; ++kb) {
    #pragma unroll
    for (int j = 0; j < 8; ++j) {
      int k = kb * 32 + (l >> 4) * 8 + j;
      float uv = U[k * G4H + colU];
      unsigned short h16 = f2bf(uv);
      bhi[kb][j] = (short)h16;
      blo[kb][j] = (short)f2bf(uv - bf2f(h16));
    }
  }

  // gate-phase mapping (lanes 0..31): one (hidden unit, batch) each
  const int bat = l & 7;
  const int hl  = (l >> 3) & 3;
  const int H   = Wv * 4 + hl;

  __shared__ float xh[8][4][16][4];             // per-wave C transpose
  __shared__ unsigned short hp[8][8][4];        // per-wave h_hi staging
  __shared__ unsigned short lp[8][8][4];        // per-wave h_lo staging

  float xwp[4];
  if (l < 32) {
    #pragma unroll
    for (int g = 0; g < 4; ++g)
      xwp[g] = xW[((size_t)bat * SEQ + 0) * G4H + g * HID + H];
  }

  float c = 0.f;
  for (int t = 0; t < SEQ; ++t) {
    // ---- designated poller: wave 0 of this WG; lane l watches flags[l]
    if (t > 0 && v == 0) {
      const int* fp = &flags[l];
      int guard = 0;
      for (;;) {
        int f = ld_int_cc(fp);
        if (__all(f >= t)) break;
        if (++guard > 30000) break;             // anti-deadlock bailout
      }
    }
    __syncthreads();

    float sg[4] = {0.f, 0.f, 0.f, 0.f};
    if (t > 0) {
      // ---- load A-fragments directly (dwordx4 IS the fragment, no repack)
      const unsigned short* hb = hbuf + ((t - 1) & 1) * 2048;
      const unsigned short* lb = lbuf + ((t - 1) & 1) * 2048;
      short8 ah[8], al[8];
      #pragma unroll
      for (int kb = 0; kb < 8; ++kb) {
        int off = ((l & 7) * 64 + kb * 8 + (l >> 4) * 2) * 4;
        ah[kb] = ld16_cc(hb + off);
        al[kb] = ld16_cc(lb + off);
      }
      asm volatile("s_waitcnt vmcnt(0)" ::: "memory");
      __builtin_amdgcn_sched_barrier(0);
      // ---- 3 independent MFMA chains (depth 8 each), summed
      f32x4 a1 = {0.f, 0.f, 0.f, 0.f};
      f32x4 a2 = {0.f, 0.f, 0.f, 0.f};
      f32x4 a3 = {0.f, 0.f, 0.f, 0.f};
      #pragma unroll
      for (int kb = 0; kb < 8; ++kb) {
        a1 = __builtin_amdgcn_mfma_f32_16x16x32_bf16(ah[kb], bhi[kb], a1, 0, 0, 0);
        a2 = __builtin_amdgcn_mfma_f32_16x16x32_bf16(ah[kb], blo[kb], a2, 0, 0, 0);
        a3 = __builtin_amdgcn_mfma_f32_16x16x32_bf16(al[kb], bhi[kb], a3, 0, 0, 0);
      }
      f32x4 acc = a1 + a2 + a3;
      // ---- intra-wave C transpose through LDS (no barrier: same wave)
      *(f32x4*)&xh[v][l >> 4][c16][0] = acc;
      asm volatile("s_waitcnt lgkmcnt(0)" ::: "memory");
      __builtin_amdgcn_sched_barrier(0);
      if (l < 32) {
        #pragma unroll
        for (int g = 0; g < 4; ++g)
          sg[g] = xh[v][bat >> 2][hl * 4 + g][bat & 3];
      }
    }

    unsigned short hhi = 0;
    if (l < 32) {
      float iv = fsigmoid(sg[0] + xwp[0]);
      float fv = fsigmoid(sg[1] + xwp[1]);
      float gv = ftanh   (sg[2] + xwp[2]);
      float ov = fsigmoid(sg[3] + xwp[3]);
      c = fv * c + iv * gv;
      float h = ov * ftanh(c);
      hhi = f2bf(h);
      hp[v][bat][hl] = hhi;
      lp[v][bat][hl] = f2bf(h - bf2f(hhi));
    }
    asm volatile("s_waitcnt lgkmcnt(0)" ::: "memory");
    __builtin_amdgcn_sched_barrier(0);
    if (l < 8) {
      unsigned h0 = hp[v][l][0], h1 = hp[v][l][1], h2 = hp[v][l][2], h3 = hp[v][l][3];
      unsigned o0 = lp[v][l][0], o1 = lp[v][l][1], o2 = lp[v][l][2], o3 = lp[v][l][3];
      i32x2 rh, rl;
      rh.x = (int)((h1 << 16) | h0); rh.y = (int)((h3 << 16) | h2);
      rl.x = (int)((o1 << 16) | o0); rl.y = (int)((o3 << 16) | o2);
      st8_cc(hbuf + (t & 1) * 2048 + (l * 64 + Wv) * 4, rh);
      st8_cc(lbuf + (t & 1) * 2048 + (l * 64 + Wv) * 4, rl);
    }
    // per-wave drain, then per-wave flag publish (no barrier on this path)
    asm volatile("s_waitcnt vmcnt(0)" ::: "memory");
    if (l == 0) st_int_cc(&flags[Wv], t + 1);
    // off-critical-path: hidden store + next xW prefetch
    if (l < 32) {
      hidden[((size_t)bat * SEQ + t) * HID + H] = hhi;
      int tn = (t + 1 < SEQ) ? t + 1 : t;
      #pragma unroll
      for (int g = 0; g < 4; ++g)
        xwp[g] = xW[((size_t)bat * SEQ + tn) * G4H + g * HID + H];
    }
  }
}

// ---------------- Kernel 4: hidden @ w_linear^T + bias -> out (bf16 MFMA, f32 out)
__global__ __launch_bounds__(256) void k_gemm_out(
    const unsigned short* __restrict__ A,   // [8192][256] bf16
    const unsigned short* __restrict__ BT,  // [32000][256] bf16
    const float* __restrict__ bias, float* __restrict__ C) {
  const int n0 = blockIdx.x * 128;
  const int m0 = blockIdx.y * 128;
  const int tid = threadIdx.x;
  const int l = tid & 63, wv = tid >> 6;
  const int wr = wv >> 1, wc = wv & 1;
  __shared__ unsigned short As[128 * 72];
  __shared__ unsigned short Bs[128 * 72];
  f32x4 acc[4][4] = {};
  const int r = tid >> 1, seg = tid & 1;
  for (int kt = 0; kt < 4; ++kt) {
    int k0 = kt * 64;
    #pragma unroll
    for (int i = 0; i < 4; ++i) {
      *(short8*)&As[r * 72 + seg * 32 + i * 8] =
          *(const short8*)&A[(size_t)(m0 + r) * HID + k0 + seg * 32 + i * 8];
      *(short8*)&Bs[r * 72 + seg * 32 + i * 8] =
          *(const short8*)&BT[(size_t)(n0 + r) * HID + k0 + seg * 32 + i * 8];
    }
    __syncthreads();
    #pragma unroll
    for (int kb = 0; kb < 2; ++kb) {
      short8 af[4], bf[4];
      #pragma unroll
      for (int mi = 0; mi < 4; ++mi)
        af[mi] = *(const short8*)&As[(wr * 64 + mi * 16 + (l & 15)) * 72 +
                                     kb * 32 + (l >> 4) * 8];
      #pragma unroll
      for (int ni = 0; ni < 4; ++ni)
        bf[ni] = *(const short8*)&Bs[(wc * 64 + ni * 16 + (l & 15)) * 72 +
                                     kb * 32 + (l >> 4) * 8];
      #pragma unroll
      for (int mi = 0; mi < 4; ++mi)
        #pragma unroll
        for (int ni = 0; ni < 4; ++ni)
          acc[mi][ni] = __builtin_amdgcn_mfma_f32_16x16x32_bf16(
              af[mi], bf[ni], acc[mi][ni], 0, 0, 0);
    }
    __syncthreads();
  }
  #pragma unroll
  for (int ni = 0; ni < 4; ++ni) {
    int n = n0 + wc * 64 + ni * 16 + (l & 15);
    float bi = bias[n];
    #pragma unroll
    for (int mi = 0; mi < 4; ++mi) {
      int mbase = m0 + wr * 64 + mi * 16 + (l >> 4) * 4;
      #pragma unroll
      for (int q = 0; q < 4; ++q)
        C[(size_t)(mbase + q) * VOCAB + n] = acc[mi][ni][q] + bi;
    }
  }
}

extern "C" void kernel_launch(void* const* d_in, const int* in_sizes, int n_in,
                              void* d_out, int out_size, void* d_ws, size_t ws_size,
                              hipStream_t stream) {
  const int*   sent = (const int*)d_in[0];
  const float* wemb = (const float*)d_in[1];
  const float* W    = (const float*)d_in[2];
  const float* U    = (const float*)d_in[3];
  const float* bias = (const float*)d_in[4];
  const float* wlin = (const float*)d_in[5];
  const float* blin = (const float*)d_in[6];
  float* out = (float*)d_out;

  // xW (32 MB f32) lives in d_out scratch; GEMM overwrites all of d_out later.
  float* xW = out;

  char* ws = (char*)d_ws;
  unsigned short* BT     = (unsigned short*)ws;                    // 16,384,000 B
  unsigned short* hidden = (unsigned short*)(ws + 16384000);       //  4,194,304 B
  // each record buffer padded to 16 KiB (only 8 KiB used)
  unsigned short* hbuf   = (unsigned short*)(ws + 16384000 + 4194304);
  unsigned short* lbuf   = (unsigned short*)(ws + 16384000 + 4194304 + 16384);
  int* flags             = (int*)(ws + 16384000 + 4194304 + 32768);   // 256 B + pad

  hipMemsetAsync(flags, 0, 256, stream);            // per-wave flags := 0
  k_embed_xw<<<2048, 256, 0, stream>>>(sent, wemb, W, bias, xW);
  k_transpose_w<<<dim3(500, 4), 256, 0, stream>>>(wlin, BT);
  k_scan<<<8, 512, 0, stream>>>(xW, U, hidden, hbuf, lbuf, flags);
  k_gemm_out<<<dim3(250, 64), 256, 0, stream>>>(hidden, BT, blin, out);
}

// Round 8
// 4402.913 us; speedup vs baseline: 1.5233x; 1.5233x over previous
//
#include <hip/hip_runtime.h>
#include <hip/hip_bf16.h>

#define VOCAB 32000
#define EMB   128
#define HID   256
#define G4H   1024
#define BS    8
#define SEQ   1024
#define NWG   8

typedef __attribute__((ext_vector_type(8))) short short8;
typedef __attribute__((ext_vector_type(4))) float f32x4;
typedef __attribute__((ext_vector_type(2))) int   i32x2;
typedef __attribute__((ext_vector_type(4))) int   i32x4;

static __device__ __forceinline__ unsigned short f2bf(float x) {
  union { __hip_bfloat16 b; unsigned short u; } cv;
  cv.b = __float2bfloat16(x);
  return cv.u;
}
static __device__ __forceinline__ float bf2f(unsigned short u) {
  union { unsigned short u; __hip_bfloat16 b; } cv;
  cv.u = u;
  return __bfloat162float(cv.b);
}

static __device__ __forceinline__ float fsigmoid(float x) {
  return 1.f / (1.f + __expf(-x));
}
static __device__ __forceinline__ float ftanh(float x) {
  return 2.f / (1.f + __expf(-2.f * x)) - 1.f;
}

// ---- LLC-direct helpers (coherence point; no cache maintenance).
static __device__ __forceinline__ int ld_int_cc(const int* p) {
  int r;
  asm volatile("global_load_dword %0, %1, off sc0 sc1\n\ts_waitcnt vmcnt(0)"
               : "=v"(r) : "v"(p) : "memory");
  return r;
}
static __device__ __forceinline__ void st_int_cc(int* p, int v) {
  asm volatile("global_store_dword %0, %1, off sc0 sc1" :: "v"(p), "v"(v) : "memory");
}
static __device__ __forceinline__ i32x2 ld8_cc(const unsigned short* p) {
  i32x2 r;
  asm volatile("global_load_dwordx2 %0, %1, off sc0 sc1" : "=v"(r) : "v"(p) : "memory");
  return r;
}
static __device__ __forceinline__ void st8_cc(unsigned short* p, i32x2 v) {
  asm volatile("global_store_dwordx2 %0, %1, off sc0 sc1" :: "v"(p), "v"(v) : "memory");
}

// ---------------- Kernel 1: embedding gather + x@W + bias -> xW (f32, in d_out scratch)
__global__ __launch_bounds__(256) void k_embed_xw(
    const int* __restrict__ sent, const float* __restrict__ wemb,
    const float* __restrict__ W, const float* __restrict__ bias,
    float* __restrict__ xW) {
  int tid = threadIdx.x;
  int blk = blockIdx.x;          // 2048 blocks
  int b  = blk >> 8;
  int t0 = (blk & 255) << 2;     // 4 timesteps per block
  __shared__ float xs[4][EMB];
  #pragma unroll
  for (int i = 0; i < 2; ++i) {
    int flat = tid + (i << 8);
    int r = flat >> 7, e = flat & 127;
    int idx = sent[b * SEQ + t0 + r];
    xs[r][e] = wemb[idx * EMB + e];
  }
  __syncthreads();
  int g0 = tid << 2;
  float acc[4][4] = {};
  for (int e = 0; e < EMB; ++e) {
    float4 w4 = *(const float4*)&W[e * G4H + g0];
    #pragma unroll
    for (int r = 0; r < 4; ++r) {
      float xv = xs[r][e];
      acc[r][0] += xv * w4.x; acc[r][1] += xv * w4.y;
      acc[r][2] += xv * w4.z; acc[r][3] += xv * w4.w;
    }
  }
  float4 bi = *(const float4*)&bias[g0];
  #pragma unroll
  for (int r = 0; r < 4; ++r) {
    float4 o;
    o.x = acc[r][0] + bi.x; o.y = acc[r][1] + bi.y;
    o.z = acc[r][2] + bi.z; o.w = acc[r][3] + bi.w;
    *(float4*)&xW[(size_t)(b * SEQ + t0 + r) * G4H + g0] = o;
  }
}

// ---------------- Kernel 2: w_linear (256 x 32000 f32) -> BT (32000 x 256 bf16)
__global__ __launch_bounds__(256) void k_transpose_w(
    const float* __restrict__ w, unsigned short* __restrict__ BT) {
  __shared__ unsigned short tile[64][66];
  int n0 = blockIdx.x * 64, k0 = blockIdx.y * 64;
  int tid = threadIdx.x;
  #pragma unroll
  for (int i = 0; i < 16; ++i) {
    int flat = tid + i * 256;
    int kk = flat >> 6, nn = flat & 63;
    tile[kk][nn] = f2bf(w[(size_t)(k0 + kk) * VOCAB + n0 + nn]);
  }
  __syncthreads();
  #pragma unroll
  for (int i = 0; i < 16; ++i) {
    int flat = tid + i * 256;
    int nn = flat >> 6, kk = flat & 63;
    BT[(size_t)(n0 + nn) * HID + k0 + kk] = tile[kk][nn];
  }
}

// ---------------- Kernel 3: persistent LSTM scan (R1 protocol + payload opts).
// 8 WGs x 512 threads = 64 waves; wave Wv owns hidden units [Wv*4, Wv*4+4) for
// all 4 gates (column-permuted U). Records line-partitioned: wave Wv's 8
// records (bat 0..7, 8B each) = ONE 64B line per buffer (single-writer lines).
// Per step: [if t>0: v0-wave polls 8 WG-flags (one line) -> barrier A ->
// fragment loads -> 3-chain MFMA -> intra-wave LDS transpose -> gates] ->
// pack -> record stores -> drain -> barrier B -> tid0 WG-flag -> off-path
// hidden store + xW prefetch.
__global__ __launch_bounds__(512) void k_scan(
    const float* __restrict__ xW, const float* __restrict__ U,
    unsigned short* __restrict__ hidden,   // [8192][256] bf16
    unsigned short* __restrict__ hbuf,     // [2][64 W][8 bat][4] hi
    unsigned short* __restrict__ lbuf,     // [2][64 W][8 bat][4] lo
    int* __restrict__ flags) {             // [8] per-WG step counters (1 line)
  const int w = blockIdx.x;
  const int tid = threadIdx.x;
  const int l = tid & 63, v = tid >> 6;
  const int Wv = w * 8 + v;                // global wave id 0..63

  // persistent U B-fragments (split bf16 hi/lo); wave's 16 cols:
  // c16 = hid_local*4 + gate  ->  U column = gate*HID + Wv*4 + hid_local
  const int c16 = l & 15;
  const int colU = (c16 & 3) * HID + Wv * 4 + (c16 >> 2);
  short8 bhi[8], blo[8];
  #pragma unroll
  for (int kb = 0; kb < 8; ++kb) {
    #pragma unroll
    for (int j = 0; j < 8; ++j) {
      int k = kb * 32 + (l >> 4) * 8 + j;
      float uv = U[k * G4H + colU];
      unsigned short h16 = f2bf(uv);
      bhi[kb][j] = (short)h16;
      blo[kb][j] = (short)f2bf(uv - bf2f(h16));
    }
  }

  // gate-phase mapping (lanes 0..31): one (hidden unit, batch) each
  const int bat = l & 7;
  const int hl  = (l >> 3) & 3;
  const int H   = Wv * 4 + hl;

  __shared__ float xh[8][4][16][4];             // per-wave C transpose
  __shared__ unsigned short hp[8][8][4];        // per-wave h_hi staging
  __shared__ unsigned short lp[8][8][4];        // per-wave h_lo staging

  float xwp[4];
  if (l < 32) {
    #pragma unroll
    for (int g = 0; g < 4; ++g)
      xwp[g] = xW[((size_t)bat * SEQ + 0) * G4H + g * HID + H];
  }

  float c = 0.f;
  for (int t = 0; t < SEQ; ++t) {
    float sg[4] = {0.f, 0.f, 0.f, 0.f};
    if (t > 0) {
      // ---- designated poller: wave 0 of this WG; lanes 0..7 watch flags
      if (v == 0) {
        const int* fp = &flags[l & 7];
        int guard = 0;
        for (;;) {
          int f = ld_int_cc(fp);
          if (__all(f >= t)) break;
          if (++guard > 30000) break;           // anti-deadlock bailout
        }
      }
      __syncthreads();                          // barrier A: poll done

      // ---- load A-fragments: per kb, two 8B records from hbuf + lbuf
      const unsigned short* hb = hbuf + ((t - 1) & 1) * 2048;
      const unsigned short* lb = lbuf + ((t - 1) & 1) * 2048;
      short8 ah[8], al[8];
      #pragma unroll
      for (int kb = 0; kb < 8; ++kb) {
        int W0 = kb * 8 + (l >> 4) * 2;
        i32x2 h0 = ld8_cc(hb + (W0 * 8 + bat) * 4);
        i32x2 h1 = ld8_cc(hb + ((W0 + 1) * 8 + bat) * 4);
        i32x2 o0 = ld8_cc(lb + (W0 * 8 + bat) * 4);
        i32x2 o1 = ld8_cc(lb + ((W0 + 1) * 8 + bat) * 4);
        union { i32x4 i; short8 s; } uh, ul;
        uh.i.x = h0.x; uh.i.y = h0.y; uh.i.z = h1.x; uh.i.w = h1.y;
        ul.i.x = o0.x; ul.i.y = o0.y; ul.i.z = o1.x; ul.i.w = o1.y;
        ah[kb] = uh.s; al[kb] = ul.s;
      }
      asm volatile("s_waitcnt vmcnt(0)" ::: "memory");
      __builtin_amdgcn_sched_barrier(0);
      // ---- 3 independent MFMA chains (depth 8 each), summed
      f32x4 a1 = {0.f, 0.f, 0.f, 0.f};
      f32x4 a2 = {0.f, 0.f, 0.f, 0.f};
      f32x4 a3 = {0.f, 0.f, 0.f, 0.f};
      #pragma unroll
      for (int kb = 0; kb < 8; ++kb) {
        a1 = __builtin_amdgcn_mfma_f32_16x16x32_bf16(ah[kb], bhi[kb], a1, 0, 0, 0);
        a2 = __builtin_amdgcn_mfma_f32_16x16x32_bf16(ah[kb], blo[kb], a2, 0, 0, 0);
        a3 = __builtin_amdgcn_mfma_f32_16x16x32_bf16(al[kb], bhi[kb], a3, 0, 0, 0);
      }
      f32x4 acc = a1 + a2 + a3;
      // ---- intra-wave C transpose through LDS (no barrier: same wave)
      *(f32x4*)&xh[v][l >> 4][c16][0] = acc;
      asm volatile("s_waitcnt lgkmcnt(0)" ::: "memory");
      __builtin_amdgcn_sched_barrier(0);
      if (l < 32) {
        #pragma unroll
        for (int g = 0; g < 4; ++g)
          sg[g] = xh[v][bat >> 2][hl * 4 + g][bat & 3];
      }
    }

    unsigned short hhi = 0;
    if (l < 32) {
      float iv = fsigmoid(sg[0] + xwp[0]);
      float fv = fsigmoid(sg[1] + xwp[1]);
      float gv = ftanh   (sg[2] + xwp[2]);
      float ov = fsigmoid(sg[3] + xwp[3]);
      c = fv * c + iv * gv;
      float h = ov * ftanh(c);
      hhi = f2bf(h);
      hp[v][bat][hl] = hhi;
      lp[v][bat][hl] = f2bf(h - bf2f(hhi));
    }
    asm volatile("s_waitcnt lgkmcnt(0)" ::: "memory");
    __builtin_amdgcn_sched_barrier(0);
    if (l < 8) {
      unsigned h0 = hp[v][l][0], h1 = hp[v][l][1], h2 = hp[v][l][2], h3 = hp[v][l][3];
      unsigned o0 = lp[v][l][0], o1 = lp[v][l][1], o2 = lp[v][l][2], o3 = lp[v][l][3];
      i32x2 rh, rl;
      rh.x = (int)((h1 << 16) | h0); rh.y = (int)((h3 << 16) | h2);
      rl.x = (int)((o1 << 16) | o0); rl.y = (int)((o3 << 16) | o2);
      st8_cc(hbuf + (t & 1) * 2048 + (Wv * 8 + l) * 4, rh);
      st8_cc(lbuf + (t & 1) * 2048 + (Wv * 8 + l) * 4, rl);
    }
    // drain all waves' record stores, then WG barrier, then ONE flag store
    asm volatile("s_waitcnt vmcnt(0)" ::: "memory");
    __syncthreads();                            // barrier B
    if (tid == 0) st_int_cc(&flags[w], t + 1);
    // off-critical-path: hidden store + next xW prefetch
    if (l < 32) {
      hidden[((size_t)bat * SEQ + t) * HID + H] = hhi;
      int tn = (t + 1 < SEQ) ? t + 1 : t;
      #pragma unroll
      for (int g = 0; g < 4; ++g)
        xwp[g] = xW[((size_t)bat * SEQ + tn) * G4H + g * HID + H];
    }
  }
}

// ---------------- Kernel 4: hidden @ w_linear^T + bias -> out (bf16 MFMA, f32 out)
__global__ __launch_bounds__(256) void k_gemm_out(
    const unsigned short* __restrict__ A,   // [8192][256] bf16
    const unsigned short* __restrict__ BT,  // [32000][256] bf16
    const float* __restrict__ bias, float* __restrict__ C) {
  const int n0 = blockIdx.x * 128;
  const int m0 = blockIdx.y * 128;
  const int tid = threadIdx.x;
  const int l = tid & 63, wv = tid >> 6;
  const int wr = wv >> 1, wc = wv & 1;
  __shared__ unsigned short As[128 * 72];
  __shared__ unsigned short Bs[128 * 72];
  f32x4 acc[4][4] = {};
  const int r = tid >> 1, seg = tid & 1;
  for (int kt = 0; kt < 4; ++kt) {
    int k0 = kt * 64;
    #pragma unroll
    for (int i = 0; i < 4; ++i) {
      *(short8*)&As[r * 72 + seg * 32 + i * 8] =
          *(const short8*)&A[(size_t)(m0 + r) * HID + k0 + seg * 32 + i * 8];
      *(short8*)&Bs[r * 72 + seg * 32 + i * 8] =
          *(const short8*)&BT[(size_t)(n0 + r) * HID + k0 + seg * 32 + i * 8];
    }
    __syncthreads();
    #pragma unroll
    for (int kb = 0; kb < 2; ++kb) {
      short8 af[4], bf[4];
      #pragma unroll
      for (int mi = 0; mi < 4; ++mi)
        af[mi] = *(const short8*)&As[(wr * 64 + mi * 16 + (l & 15)) * 72 +
                                     kb * 32 + (l >> 4) * 8];
      #pragma unroll
      for (int ni = 0; ni < 4; ++ni)
        bf[ni] = *(const short8*)&Bs[(wc * 64 + ni * 16 + (l & 15)) * 72 +
                                     kb * 32 + (l >> 4) * 8];
      #pragma unroll
      for (int mi = 0; mi < 4; ++mi)
        #pragma unroll
        for (int ni = 0; ni < 4; ++ni)
          acc[mi][ni] = __builtin_amdgcn_mfma_f32_16x16x32_bf16(
              af[mi], bf[ni], acc[mi][ni], 0, 0, 0);
    }
    __syncthreads();
  }
  #pragma unroll
  for (int ni = 0; ni < 4; ++ni) {
    int n = n0 + wc * 64 + ni * 16 + (l & 15);
    float bi = bias[n];
    #pragma unroll
    for (int mi = 0; mi < 4; ++mi) {
      int mbase = m0 + wr * 64 + mi * 16 + (l >> 4) * 4;
      #pragma unroll
      for (int q = 0; q < 4; ++q)
        C[(size_t)(mbase + q) * VOCAB + n] = acc[mi][ni][q] + bi;
    }
  }
}

extern "C" void kernel_launch(void* const* d_in, const int* in_sizes, int n_in,
                              void* d_out, int out_size, void* d_ws, size_t ws_size,
                              hipStream_t stream) {
  const int*   sent = (const int*)d_in[0];
  const float* wemb = (const float*)d_in[1];
  const float* W    = (const float*)d_in[2];
  const float* U    = (const float*)d_in[3];
  const float* bias = (const float*)d_in[4];
  const float* wlin = (const float*)d_in[5];
  const float* blin = (const float*)d_in[6];
  float* out = (float*)d_out;

  // xW (32 MB f32) lives in d_out scratch; GEMM overwrites all of d_out later.
  float* xW = out;

  char* ws = (char*)d_ws;
  unsigned short* BT     = (unsigned short*)ws;                    // 16,384,000 B
  unsigned short* hidden = (unsigned short*)(ws + 16384000);       //  4,194,304 B
  // record buffers: 2 x 4KB each, padded to 16KB apart
  unsigned short* hbuf   = (unsigned short*)(ws + 16384000 + 4194304);
  unsigned short* lbuf   = (unsigned short*)(ws + 16384000 + 4194304 + 16384);
  int* flags             = (int*)(ws + 16384000 + 4194304 + 32768);   // 32 B

  hipMemsetAsync(flags, 0, 32, stream);             // WG flags := 0
  k_embed_xw<<<2048, 256, 0, stream>>>(sent, wemb, W, bias, xW);
  k_transpose_w<<<dim3(500, 4), 256, 0, stream>>>(wlin, BT);
  k_scan<<<NWG, 512, 0, stream>>>(xW, U, hidden, hbuf, lbuf, flags);
  k_gemm_out<<<dim3(250, 64), 256, 0, stream>>>(hidden, BT, blin, out);
}

// Round 9
// 3437.731 us; speedup vs baseline: 1.9510x; 1.2808x over previous
//
#include <hip/hip_runtime.h>
#include <hip/hip_bf16.h>

#define VOCAB 32000
#define EMB   128
#define HID   256
#define G4H   1024
#define BS    8
#define SEQ   1024
#define NWG   8

typedef __attribute__((ext_vector_type(8))) short short8;
typedef __attribute__((ext_vector_type(4))) float f32x4;
typedef __attribute__((ext_vector_type(2))) int   i32x2;

static __device__ __forceinline__ unsigned short f2bf(float x) {
  union { __hip_bfloat16 b; unsigned short u; } cv;
  cv.b = __float2bfloat16(x);
  return cv.u;
}
static __device__ __forceinline__ float bf2f(unsigned short u) {
  union { unsigned short u; __hip_bfloat16 b; } cv;
  cv.u = u;
  return __bfloat162float(cv.b);
}

static __device__ __forceinline__ float fsigmoid(float x) {
  return 1.f / (1.f + __expf(-x));
}
static __device__ __forceinline__ float ftanh(float x) {
  return 2.f / (1.f + __expf(-2.f * x)) - 1.f;
}

// ---- LLC-direct helpers (coherence point; no cache maintenance).
static __device__ __forceinline__ int ld_int_cc(const int* p) {
  int r;
  asm volatile("global_load_dword %0, %1, off sc0 sc1\n\ts_waitcnt vmcnt(0)"
               : "=v"(r) : "v"(p) : "memory");
  return r;
}
static __device__ __forceinline__ void st_int_cc(int* p, int v) {
  asm volatile("global_store_dword %0, %1, off sc0 sc1" :: "v"(p), "v"(v) : "memory");
}
static __device__ __forceinline__ short8 ld16_cc(const unsigned short* p) {
  short8 r;
  asm volatile("global_load_dwordx4 %0, %1, off sc0 sc1" : "=v"(r) : "v"(p) : "memory");
  return r;
}
static __device__ __forceinline__ void st8_cc(unsigned short* p, i32x2 v) {
  asm volatile("global_store_dwordx2 %0, %1, off sc0 sc1" :: "v"(p), "v"(v) : "memory");
}

// ---------------- Kernel 1: embedding gather + x@W + bias -> xW (f32, in d_out scratch)
__global__ __launch_bounds__(256) void k_embed_xw(
    const int* __restrict__ sent, const float* __restrict__ wemb,
    const float* __restrict__ W, const float* __restrict__ bias,
    float* __restrict__ xW) {
  int tid = threadIdx.x;
  int blk = blockIdx.x;          // 2048 blocks
  int b  = blk >> 8;
  int t0 = (blk & 255) << 2;     // 4 timesteps per block
  __shared__ float xs[4][EMB];
  #pragma unroll
  for (int i = 0; i < 2; ++i) {
    int flat = tid + (i << 8);
    int r = flat >> 7, e = flat & 127;
    int idx = sent[b * SEQ + t0 + r];
    xs[r][e] = wemb[idx * EMB + e];
  }
  __syncthreads();
  int g0 = tid << 2;
  float acc[4][4] = {};
  for (int e = 0; e < EMB; ++e) {
    float4 w4 = *(const float4*)&W[e * G4H + g0];
    #pragma unroll
    for (int r = 0; r < 4; ++r) {
      float xv = xs[r][e];
      acc[r][0] += xv * w4.x; acc[r][1] += xv * w4.y;
      acc[r][2] += xv * w4.z; acc[r][3] += xv * w4.w;
    }
  }
  float4 bi = *(const float4*)&bias[g0];
  #pragma unroll
  for (int r = 0; r < 4; ++r) {
    float4 o;
    o.x = acc[r][0] + bi.x; o.y = acc[r][1] + bi.y;
    o.z = acc[r][2] + bi.z; o.w = acc[r][3] + bi.w;
    *(float4*)&xW[(size_t)(b * SEQ + t0 + r) * G4H + g0] = o;
  }
}

// ---------------- Kernel 2: w_linear (256 x 32000 f32) -> BT (32000 x 256 bf16)
__global__ __launch_bounds__(256) void k_transpose_w(
    const float* __restrict__ w, unsigned short* __restrict__ BT) {
  __shared__ unsigned short tile[64][66];
  int n0 = blockIdx.x * 64, k0 = blockIdx.y * 64;
  int tid = threadIdx.x;
  #pragma unroll
  for (int i = 0; i < 16; ++i) {
    int flat = tid + i * 256;
    int kk = flat >> 6, nn = flat & 63;
    tile[kk][nn] = f2bf(w[(size_t)(k0 + kk) * VOCAB + n0 + nn]);
  }
  __syncthreads();
  #pragma unroll
  for (int i = 0; i < 16; ++i) {
    int flat = tid + i * 256;
    int nn = flat >> 6, kk = flat & 63;
    BT[(size_t)(n0 + nn) * HID + k0 + kk] = tile[kk][nn];
  }
}

// ---------------- Kernel 3: persistent LSTM scan.
// 8 WGs x 512 threads = 64 waves; wave Wv owns hidden units [Wv*4, Wv*4+4) for
// all 4 gates (column-permuted U). Record layout [2 buf][32 kq][8 bat][8 j]
// (kq=H>>3, j=H&7): reader's dwordx4 IS the MFMA A-fragment (no repack, the
// R7 regression); writer's 4 H-values are j-contiguous -> one dwordx2 per bat.
// Sync = R1's proven skeleton: v0-wave polls 8 WG-flags (one line) ->
// barrier A -> dense loads -> 3-chain MFMA -> intra-wave transpose -> gates ->
// LDS pack -> dwordx2 stores -> drain -> barrier B -> tid0 WG-flag.
__global__ __launch_bounds__(512) void k_scan(
    const float* __restrict__ xW, const float* __restrict__ U,
    unsigned short* __restrict__ hidden,   // [8192][256] bf16
    unsigned short* __restrict__ hbuf,     // [2][32 kq][8 bat][8 j] hi
    unsigned short* __restrict__ lbuf,     // [2][32 kq][8 bat][8 j] lo
    int* __restrict__ flags) {             // [8] per-WG step counters (1 line)
  const int w = blockIdx.x;
  const int tid = threadIdx.x;
  const int l = tid & 63, v = tid >> 6;
  const int Wv = w * 8 + v;                // global wave id 0..63

  // persistent U B-fragments (split bf16 hi/lo); wave's 16 cols:
  // c16 = hid_local*4 + gate  ->  U column = gate*HID + Wv*4 + hid_local
  const int c16 = l & 15;
  const int colU = (c16 & 3) * HID + Wv * 4 + (c16 >> 2);
  short8 bhi[8], blo[8];
  #pragma unroll
  for (int kb = 0; kb < 8; ++kb) {
    #pragma unroll
    for (int j = 0; j < 8; ++j) {
      int k = kb * 32 + (l >> 4) * 8 + j;
      float uv = U[k * G4H + colU];
      unsigned short h16 = f2bf(uv);
      bhi[kb][j] = (short)h16;
      blo[kb][j] = (short)f2bf(uv - bf2f(h16));
    }
  }

  // gate-phase mapping (lanes 0..31): one (hidden unit, batch) each
  const int bat = l & 7;
  const int hl  = (l >> 3) & 3;
  const int H   = Wv * 4 + hl;

  __shared__ float xh[8][4][16][4];             // per-wave C transpose
  __shared__ unsigned short hp[8][8][4];        // per-wave h_hi staging
  __shared__ unsigned short lp[8][8][4];        // per-wave h_lo staging

  float xwp[4];
  if (l < 32) {
    #pragma unroll
    for (int g = 0; g < 4; ++g)
      xwp[g] = xW[((size_t)bat * SEQ + 0) * G4H + g * HID + H];
  }

  float c = 0.f;
  for (int t = 0; t < SEQ; ++t) {
    float sg[4] = {0.f, 0.f, 0.f, 0.f};
    if (t > 0) {
      // ---- designated poller: wave 0 of this WG; lanes watch the flag line
      if (v == 0) {
        const int* fp = &flags[l & 7];
        int guard = 0;
        for (;;) {
          int f = ld_int_cc(fp);
          if (__all(f >= t)) break;
          if (++guard > 30000) break;           // anti-deadlock bailout
        }
      }
      __syncthreads();                          // barrier A: step data ready

      // ---- dense A-fragment loads: dwordx4 == fragment (row = bat, dup x2)
      const unsigned short* hb = hbuf + ((t - 1) & 1) * 2048;
      const unsigned short* lb = lbuf + ((t - 1) & 1) * 2048;
      short8 ah[8], al[8];
      #pragma unroll
      for (int kb = 0; kb < 8; ++kb) {
        int off = ((kb * 4 + (l >> 4)) * 8 + (l & 7)) * 8;
        ah[kb] = ld16_cc(hb + off);
        al[kb] = ld16_cc(lb + off);
      }
      asm volatile("s_waitcnt vmcnt(0)" ::: "memory");
      __builtin_amdgcn_sched_barrier(0);
      // ---- 3 independent MFMA chains (depth 8 each), summed
      f32x4 a1 = {0.f, 0.f, 0.f, 0.f};
      f32x4 a2 = {0.f, 0.f, 0.f, 0.f};
      f32x4 a3 = {0.f, 0.f, 0.f, 0.f};
      #pragma unroll
      for (int kb = 0; kb < 8; ++kb) {
        a1 = __builtin_amdgcn_mfma_f32_16x16x32_bf16(ah[kb], bhi[kb], a1, 0, 0, 0);
        a2 = __builtin_amdgcn_mfma_f32_16x16x32_bf16(ah[kb], blo[kb], a2, 0, 0, 0);
        a3 = __builtin_amdgcn_mfma_f32_16x16x32_bf16(al[kb], bhi[kb], a3, 0, 0, 0);
      }
      f32x4 acc = a1 + a2 + a3;
      // ---- intra-wave C transpose through LDS (no barrier: same wave)
      *(f32x4*)&xh[v][l >> 4][c16][0] = acc;
      asm volatile("s_waitcnt lgkmcnt(0)" ::: "memory");
      __builtin_amdgcn_sched_barrier(0);
      if (l < 32) {
        #pragma unroll
        for (int g = 0; g < 4; ++g)
          sg[g] = xh[v][bat >> 2][hl * 4 + g][bat & 3];
      }
    }

    unsigned short hhi = 0;
    if (l < 32) {
      float iv = fsigmoid(sg[0] + xwp[0]);
      float fv = fsigmoid(sg[1] + xwp[1]);
      float gv = ftanh   (sg[2] + xwp[2]);
      float ov = fsigmoid(sg[3] + xwp[3]);
      c = fv * c + iv * gv;
      float h = ov * ftanh(c);
      hhi = f2bf(h);
      hp[v][bat][hl] = hhi;
      lp[v][bat][hl] = f2bf(h - bf2f(hhi));
    }
    asm volatile("s_waitcnt lgkmcnt(0)" ::: "memory");
    __builtin_amdgcn_sched_barrier(0);
    if (l < 8) {
      // pack this wave's 4 H-values for batch l: j-contiguous 8B store
      unsigned h0 = hp[v][l][0], h1 = hp[v][l][1], h2 = hp[v][l][2], h3 = hp[v][l][3];
      unsigned o0 = lp[v][l][0], o1 = lp[v][l][1], o2 = lp[v][l][2], o3 = lp[v][l][3];
      i32x2 rh, rl;
      rh.x = (int)((h1 << 16) | h0); rh.y = (int)((h3 << 16) | h2);
      rl.x = (int)((o1 << 16) | o0); rl.y = (int)((o3 << 16) | o2);
      int off = ((Wv >> 1) * 8 + l) * 8 + (Wv & 1) * 4;
      st8_cc(hbuf + (t & 1) * 2048 + off, rh);
      st8_cc(lbuf + (t & 1) * 2048 + off, rl);
    }
    // drain all waves' record stores, then WG barrier, then ONE flag store
    asm volatile("s_waitcnt vmcnt(0)" ::: "memory");
    __syncthreads();                            // barrier B
    if (tid == 0) st_int_cc(&flags[w], t + 1);
    // off-critical-path: hidden store + next xW prefetch
    if (l < 32) {
      hidden[((size_t)bat * SEQ + t) * HID + H] = hhi;
      int tn = (t + 1 < SEQ) ? t + 1 : t;
      #pragma unroll
      for (int g = 0; g < 4; ++g)
        xwp[g] = xW[((size_t)bat * SEQ + tn) * G4H + g * HID + H];
    }
  }
}

// ---------------- Kernel 4: hidden @ w_linear^T + bias -> out (bf16 MFMA, f32 out)
__global__ __launch_bounds__(256) void k_gemm_out(
    const unsigned short* __restrict__ A,   // [8192][256] bf16
    const unsigned short* __restrict__ BT,  // [32000][256] bf16
    const float* __restrict__ bias, float* __restrict__ C) {
  const int n0 = blockIdx.x * 128;
  const int m0 = blockIdx.y * 128;
  const int tid = threadIdx.x;
  const int l = tid & 63, wv = tid >> 6;
  const int wr = wv >> 1, wc = wv & 1;
  __shared__ unsigned short As[128 * 72];
  __shared__ unsigned short Bs[128 * 72];
  f32x4 acc[4][4] = {};
  const int r = tid >> 1, seg = tid & 1;
  for (int kt = 0; kt < 4; ++kt) {
    int k0 = kt * 64;
    #pragma unroll
    for (int i = 0; i < 4; ++i) {
      *(short8*)&As[r * 72 + seg * 32 + i * 8] =
          *(const short8*)&A[(size_t)(m0 + r) * HID + k0 + seg * 32 + i * 8];
      *(short8*)&Bs[r * 72 + seg * 32 + i * 8] =
          *(const short8*)&BT[(size_t)(n0 + r) * HID + k0 + seg * 32 + i * 8];
    }
    __syncthreads();
    #pragma unroll
    for (int kb = 0; kb < 2; ++kb) {
      short8 af[4], bf[4];
      #pragma unroll
      for (int mi = 0; mi < 4; ++mi)
        af[mi] = *(const short8*)&As[(wr * 64 + mi * 16 + (l & 15)) * 72 +
                                     kb * 32 + (l >> 4) * 8];
      #pragma unroll
      for (int ni = 0; ni < 4; ++ni)
        bf[ni] = *(const short8*)&Bs[(wc * 64 + ni * 16 + (l & 15)) * 72 +
                                     kb * 32 + (l >> 4) * 8];
      #pragma unroll
      for (int mi = 0; mi < 4; ++mi)
        #pragma unroll
        for (int ni = 0; ni < 4; ++ni)
          acc[mi][ni] = __builtin_amdgcn_mfma_f32_16x16x32_bf16(
              af[mi], bf[ni], acc[mi][ni], 0, 0, 0);
    }
    __syncthreads();
  }
  #pragma unroll
  for (int ni = 0; ni < 4; ++ni) {
    int n = n0 + wc * 64 + ni * 16 + (l & 15);
    float bi = bias[n];
    #pragma unroll
    for (int mi = 0; mi < 4; ++mi) {
      int mbase = m0 + wr * 64 + mi * 16 + (l >> 4) * 4;
      #pragma unroll
      for (int q = 0; q < 4; ++q)
        C[(size_t)(mbase + q) * VOCAB + n] = acc[mi][ni][q] + bi;
    }
  }
}

extern "C" void kernel_launch(void* const* d_in, const int* in_sizes, int n_in,
                              void* d_out, int out_size, void* d_ws, size_t ws_size,
                              hipStream_t stream) {
  const int*   sent = (const int*)d_in[0];
  const float* wemb = (const float*)d_in[1];
  const float* W    = (const float*)d_in[2];
  const float* U    = (const float*)d_in[3];
  const float* bias = (const float*)d_in[4];
  const float* wlin = (const float*)d_in[5];
  const float* blin = (const float*)d_in[6];
  float* out = (float*)d_out;

  // xW (32 MB f32) lives in d_out scratch; GEMM overwrites all of d_out later.
  float* xW = out;

  char* ws = (char*)d_ws;
  unsigned short* BT     = (unsigned short*)ws;                    // 16,384,000 B
  unsigned short* hidden = (unsigned short*)(ws + 16384000);       //  4,194,304 B
  // record buffers: 2 x 4KB each, padded 16KB apart
  unsigned short* hbuf   = (unsigned short*)(ws + 16384000 + 4194304);
  unsigned short* lbuf   = (unsigned short*)(ws + 16384000 + 4194304 + 16384);
  int* flags             = (int*)(ws + 16384000 + 4194304 + 32768);   // 32 B

  hipMemsetAsync(flags, 0, 32, stream);             // WG flags := 0
  k_embed_xw<<<2048, 256, 0, stream>>>(sent, wemb, W, bias, xW);
  k_transpose_w<<<dim3(500, 4), 256, 0, stream>>>(wlin, BT);
  k_scan<<<NWG, 512, 0, stream>>>(xW, U, hidden, hbuf, lbuf, flags);
  k_gemm_out<<<dim3(250, 64), 256, 0, stream>>>(hidden, BT, blin, out);
}